// Round 3
// baseline (184.173 us; speedup 1.0000x reference)
//
#include <hip/hip_runtime.h>

// Problem constants (fixed by the reference file).
#define BB 16
#define HH 512
#define WW 512
#define PIX_PER_THREAD 4          // 4 px * 9 fp32 = 144 B = 9 float4s per thread
#define THREADS_PER_BATCH ((HH * WW) / PIX_PER_THREAD)   // 65536
#define TOTAL_THREADS (BB * THREADS_PER_BATCH)           // 1048576
#define BLOCK 256
#define F4_PER_THREAD 9           // 9 float4 = 144 B
#define F4_PER_BLOCK (BLOCK * F4_PER_THREAD)             // 2304 float4 = 36864 B

// CALIBRATION ROUND: kernel body identical to R1 (159.7 us). kernel_launch
// dispatches it TWICE (idempotent: same values written both times). The
// dur_us delta vs R1 equals one jac duration -- this disambiguates
// "jac ~= 66 us (kernel-bound)" from "jac ~= 23 us + ~45 us harness
// restore-dispatch overhead (roofline)". Top-5 rocprof rows are all
// 92-98 us fills, so jac's own row is masked either way.

struct Px { float a00, a01, a02, a10, a11, a12, d0, d1, ff; };

__device__ __forceinline__ Px compute_px(
    float u0, float u1, float invf,
    float a0, float a1, float a2,
    float J00, float J01, float J10, float J11, float J21, float cp)
{
    const float c3 = a2;

    const float p0 = a0 - c3 * u0;
    const float p1 = a1 - c3 * u1;

    const float n2     = p0 * p0 + p1 * p1;
    const float inv_n  = rsqrtf(n2);
    const float inv_n3 = inv_n * inv_n * inv_n;
    const float M00 = inv_n - p0 * p0 * inv_n3;
    const float M01 =        -p0 * p1 * inv_n3;
    const float M11 = inv_n - p1 * p1 * inv_n3;

    const float P00 = J00;
    const float P01 = J01 + u0 * cp;
    const float P10 = J10;
    const float P11 = J11 + u1 * cp;

    Px r;
    r.a00 = M00 * P00 + M01 * P10;
    r.a01 = M00 * P01 + M01 * P11;
    r.a10 = M01 * P00 + M11 * P10;
    r.a11 = M01 * P01 + M11 * P11;

    const float q0 = c3 * u0 * invf;
    const float q1 = c3 * u1 * invf;
    r.a02 = M00 * q0 + M01 * q1;
    r.a12 = M01 * q0 + M11 * q1;

    const float nn2     = u0 * u0 + u1 * u1 + 1.0f;
    const float inv_nn  = rsqrtf(nn2);
    const float inv_nn3 = inv_nn * inv_nn * inv_nn;

    r.d0 = inv_nn * (u0 * J00 + u1 * J10);
    r.d1 = inv_nn * (u0 * J01 + u1 * J11 + J21);

    const float w0 = -u0 * invf;
    const float w1 = -u1 * invf;
    const float s  = u0 * w0 + u1 * w1;
    const float g0 = inv_nn * w0 - u0 * inv_nn3 * s;
    const float g1 = inv_nn * w1 - u1 * inv_nn3 * s;
    const float g2 =             -      inv_nn3 * s;
    r.ff = g0 * a0 + g1 * a1 + g2 * a2;

    return r;
}

__global__ __launch_bounds__(BLOCK) void jac_kernel(
    const float* __restrict__ roll,
    const float* __restrict__ pitch,
    const float* __restrict__ focal,
    float* __restrict__ out)
{
    __shared__ float4 lds4[F4_PER_BLOCK];

    const int t = blockIdx.x * BLOCK + threadIdx.x;
    const int b = t >> 16;
    const int pix0 = (t & (THREADS_PER_BATCH - 1)) * PIX_PER_THREAD;
    const int y  = pix0 >> 9;
    const int x0 = pix0 & (WW - 1);

    const float rl = roll[b];
    const float pt = pitch[b];
    const float f  = focal[b];
    const float sr = sinf(rl), cr = cosf(rl);
    const float sp = sinf(pt), cp = cosf(pt);
    const float a0 = -sr * cp, a1 = -cr * cp, a2 = -sp;
    const float J00 = -cr * cp, J01 = sr * sp;
    const float J10 =  sr * cp, J11 = cr * sp;
    const float J21 = -cp;
    const float invf = 1.0f / f;

    const float u1 = ((float)y + 0.5f - (float)HH * 0.5f) * invf;
    const float ub = ((float)x0 + 0.5f - (float)WW * 0.5f) * invf;

    const Px x  = compute_px(ub,               u1, invf, a0, a1, a2, J00, J01, J10, J11, J21, cp);
    const Px y1 = compute_px(ub +        invf, u1, invf, a0, a1, a2, J00, J01, J10, J11, J21, cp);
    const Px z  = compute_px(ub + 2.0f * invf, u1, invf, a0, a1, a2, J00, J01, J10, J11, J21, cp);
    const Px w  = compute_px(ub + 3.0f * invf, u1, invf, a0, a1, a2, J00, J01, J10, J11, J21, cp);

    const float4 v0 = make_float4(x.a00, x.a01, x.a02, x.a10);
    const float4 v1 = make_float4(x.a11, x.a12, x.d0,  x.d1 );
    const float4 v2 = make_float4(x.ff,  y1.a00, y1.a01, y1.a02);
    const float4 v3 = make_float4(y1.a10, y1.a11, y1.a12, y1.d0);
    const float4 v4 = make_float4(y1.d1,  y1.ff,  z.a00, z.a01);
    const float4 v5 = make_float4(z.a02, z.a10, z.a11, z.a12);
    const float4 v6 = make_float4(z.d0,  z.d1,  z.ff,  w.a00);
    const float4 v7 = make_float4(w.a01, w.a02, w.a10, w.a11);
    const float4 v8 = make_float4(w.a12, w.d0,  w.d1,  w.ff);

    float4* s = &lds4[threadIdx.x * F4_PER_THREAD];
    s[0] = v0; s[1] = v1; s[2] = v2; s[3] = v3; s[4] = v4;
    s[5] = v5; s[6] = v6; s[7] = v7; s[8] = v8;

    __syncthreads();

    float4* __restrict__ ob = (float4*)out + (size_t)blockIdx.x * F4_PER_BLOCK;
#pragma unroll
    for (int k = 0; k < F4_PER_THREAD; ++k) {
        const int idx = k * BLOCK + threadIdx.x;
        ob[idx] = lds4[idx];
    }
}

extern "C" void kernel_launch(void* const* d_in, const int* in_sizes, int n_in,
                              void* d_out, int out_size, void* d_ws, size_t ws_size,
                              hipStream_t stream) {
    const float* roll  = (const float*)d_in[0];
    const float* pitch = (const float*)d_in[1];
    const float* focal = (const float*)d_in[2];
    float* out = (float*)d_out;

    dim3 grid(TOTAL_THREADS / BLOCK);   // 4096
    dim3 block(BLOCK);
    // Launch TWICE: idempotent; second dispatch adds exactly one jac
    // duration to the timed region (calibration of the masked kernel time).
    jac_kernel<<<grid, block, 0, stream>>>(roll, pitch, focal, out);
    jac_kernel<<<grid, block, 0, stream>>>(roll, pitch, focal, out);
}

// Round 4
// 158.289 us; speedup vs baseline: 1.1635x; 1.1635x over previous
//
#include <hip/hip_runtime.h>

// Problem constants (fixed by the reference file).
#define BB 16
#define HH 512
#define WW 512
#define PIX_PER_THREAD 4          // 4 px * 9 fp32 = 144 B = 9 float4s per thread
#define THREADS_PER_BATCH ((HH * WW) / PIX_PER_THREAD)   // 65536
#define TOTAL_THREADS (BB * THREADS_PER_BATCH)           // 1048576
#define BLOCK 256
#define F4_PER_THREAD 9           // 9 float4 = 144 B
#define F4_PER_BLOCK (BLOCK * F4_PER_THREAD)             // 2304 float4 = 36864 B

// ROOFLINE NOTE (R3 calibration, double-dispatch delta): one jac dispatch
// = 184.2 - 159.7 = 24.5 us, vs a 151 MB / 6.6 TB/s = 22.9 us mandatory
// write floor (fill kernels in the same capture demonstrate 6.6-6.7 TB/s).
// The kernel is ~93% of its write roofline; the rest of the ~160 us timed
// region is the harness's 576 MiB re-poison fill (~93 us) + ~30 restore
// dispatches (~42 us), which the .cpp cannot touch.

struct Px { float a00, a01, a02, a10, a11, a12, d0, d1, ff; };

__device__ __forceinline__ Px compute_px(
    float u0, float u1, float invf,
    float a0, float a1, float a2,
    float J00, float J01, float J10, float J11, float J21, float cp)
{
    const float c3 = a2;

    // proj = abc[:2] - c3*uv
    const float p0 = a0 - c3 * u0;
    const float p1 = a1 - c3 * u1;

    // J_norm2proj (2x2 symmetric): I/n - vvT/n^3
    const float n2     = p0 * p0 + p1 * p1;
    const float inv_n  = rsqrtf(n2);
    const float inv_n3 = inv_n * inv_n * inv_n;
    const float M00 = inv_n - p0 * p0 * inv_n3;
    const float M01 =        -p0 * p1 * inv_n3;
    const float M11 = inv_n - p1 * p1 * inv_n3;

    // J_proj2delta = [[1,0,-u0],[0,1,-u1]] @ J_rp   (J20 = 0)
    const float P00 = J00;
    const float P01 = J01 + u0 * cp;   // J01 - u0*J21
    const float P10 = J10;
    const float P11 = J11 + u1 * cp;

    Px r;
    // J_up2delta = M @ P
    r.a00 = M00 * P00 + M01 * P10;
    r.a01 = M00 * P01 + M01 * P11;
    r.a10 = M01 * P00 + M11 * P10;
    r.a11 = M01 * P01 + M11 * P11;

    // J_proj2f = c3*uv/f ;  J_up2f = M @ J_proj2f
    const float q0 = c3 * u0 * invf;
    const float q1 = c3 * u1 * invf;
    r.a02 = M00 * q0 + M01 * q1;
    r.a12 = M01 * q0 + M11 * q1;

    // uv1 = (u0,u1,1); its vecnorm jacobian pieces
    const float nn2     = u0 * u0 + u1 * u1 + 1.0f;
    const float inv_nn  = rsqrtf(nn2);
    const float inv_nn3 = inv_nn * inv_nn * inv_nn;

    // J_delta = uv1_norm @ J_rp   (J20 = 0)
    r.d0 = inv_nn * (u0 * J00 + u1 * J10);
    r.d1 = inv_nn * (u0 * J01 + u1 * J11 + J21);

    // J_norm2f = J_norm2img @ (-uv/f);  J_f = J_norm2f . abc
    const float w0 = -u0 * invf;
    const float w1 = -u1 * invf;
    const float s  = u0 * w0 + u1 * w1;
    const float g0 = inv_nn * w0 - u0 * inv_nn3 * s;
    const float g1 = inv_nn * w1 - u1 * inv_nn3 * s;
    const float g2 =             -      inv_nn3 * s;
    r.ff = g0 * a0 + g1 * a1 + g2 * a2;

    return r;
}

__global__ __launch_bounds__(BLOCK) void jac_kernel(
    const float* __restrict__ roll,
    const float* __restrict__ pitch,
    const float* __restrict__ focal,
    float* __restrict__ out)
{
    // LDS staging for fully-coalesced global stores.
    // Slot stride per thread = 9 float4 = 36 words -> b128 write phases
    // spread across all 32 banks (8 bank-cycle floor, no net conflicts).
    __shared__ float4 lds4[F4_PER_BLOCK];

    const int t = blockIdx.x * BLOCK + threadIdx.x;
    const int b = t >> 16;                         // t / THREADS_PER_BATCH
    const int pix0 = (t & (THREADS_PER_BATCH - 1)) * PIX_PER_THREAD;
    const int y  = pix0 >> 9;                      // / WW
    const int x0 = pix0 & (WW - 1);                // 0..508, never crosses a row

    // ---- per-batch constants (wave-uniform -> scalarized by compiler) ----
    const float rl = roll[b];
    const float pt = pitch[b];
    const float f  = focal[b];
    const float sr = sinf(rl), cr = cosf(rl);
    const float sp = sinf(pt), cp = cosf(pt);
    const float a0 = -sr * cp, a1 = -cr * cp, a2 = -sp;   // abc
    // J_rp (3x2): row0=(-cr*cp, sr*sp) row1=(sr*cp, cr*sp) row2=(0, -cp)
    const float J00 = -cr * cp, J01 = sr * sp;
    const float J10 =  sr * cp, J11 = cr * sp;
    const float J21 = -cp;                                 // J20 == 0
    const float invf = 1.0f / f;

    const float u1 = ((float)y + 0.5f - (float)HH * 0.5f) * invf;
    const float ub = ((float)x0 + 0.5f - (float)WW * 0.5f) * invf;

    // ---- 4 pixels, all in named registers ----
    const Px x  = compute_px(ub,               u1, invf, a0, a1, a2, J00, J01, J10, J11, J21, cp);
    const Px y1 = compute_px(ub +        invf, u1, invf, a0, a1, a2, J00, J01, J10, J11, J21, cp);
    const Px z  = compute_px(ub + 2.0f * invf, u1, invf, a0, a1, a2, J00, J01, J10, J11, J21, cp);
    const Px w  = compute_px(ub + 3.0f * invf, u1, invf, a0, a1, a2, J00, J01, J10, J11, J21, cp);

    // ---- explicit float4 composition (words j = px*9 + comp) ----
    const float4 v0 = make_float4(x.a00, x.a01, x.a02, x.a10);   // w0..w3
    const float4 v1 = make_float4(x.a11, x.a12, x.d0,  x.d1 );   // w4..w7
    const float4 v2 = make_float4(x.ff,  y1.a00, y1.a01, y1.a02);// w8..w11
    const float4 v3 = make_float4(y1.a10, y1.a11, y1.a12, y1.d0);// w12..w15
    const float4 v4 = make_float4(y1.d1,  y1.ff,  z.a00, z.a01); // w16..w19
    const float4 v5 = make_float4(z.a02, z.a10, z.a11, z.a12);   // w20..w23
    const float4 v6 = make_float4(z.d0,  z.d1,  z.ff,  w.a00);   // w24..w27
    const float4 v7 = make_float4(w.a01, w.a02, w.a10, w.a11);   // w28..w31
    const float4 v8 = make_float4(w.a12, w.d0,  w.d1,  w.ff);    // w32..w35

    // Phase 1: registers -> LDS (AoS order, stride 36 words)
    float4* s = &lds4[threadIdx.x * F4_PER_THREAD];
    s[0] = v0; s[1] = v1; s[2] = v2; s[3] = v3; s[4] = v4;
    s[5] = v5; s[6] = v6; s[7] = v7; s[8] = v8;

    __syncthreads();

    // Phase 2: LDS -> global, block-linear => lane-contiguous float4 stores.
    float4* __restrict__ ob = (float4*)out + (size_t)blockIdx.x * F4_PER_BLOCK;
#pragma unroll
    for (int k = 0; k < F4_PER_THREAD; ++k) {
        const int idx = k * BLOCK + threadIdx.x;
        ob[idx] = lds4[idx];
    }
}

extern "C" void kernel_launch(void* const* d_in, const int* in_sizes, int n_in,
                              void* d_out, int out_size, void* d_ws, size_t ws_size,
                              hipStream_t stream) {
    const float* roll  = (const float*)d_in[0];
    const float* pitch = (const float*)d_in[1];
    const float* focal = (const float*)d_in[2];
    float* out = (float*)d_out;

    dim3 grid(TOTAL_THREADS / BLOCK);   // 4096
    dim3 block(BLOCK);
    jac_kernel<<<grid, block, 0, stream>>>(roll, pitch, focal, out);
}